// Round 6
// baseline (390.813 us; speedup 1.0000x reference)
//
#include <hip/hip_runtime.h>
#include <stdint.h>

using fx4   = __attribute__((ext_vector_type(4))) float;
using half8 = __attribute__((ext_vector_type(8))) _Float16;

__device__ __forceinline__ ushort f2h(float x) {
  _Float16 h = (_Float16)x;
  union { _Float16 hv; ushort u; } v; v.hv = h;
  return v.u;
}

__device__ __forceinline__ void gload_lds16(const ushort* g, ushort* l) {
  __builtin_amdgcn_global_load_lds(
      (__attribute__((address_space(1))) const void*)g,
      (__attribute__((address_space(3))) void*)l, 16, 0, 0);
}

#define MFMA16(a, b, c) __builtin_amdgcn_mfma_f32_16x16x32_f16(a, b, c, 0, 0, 0)

// C[m][n] = sum_k A[m][k] * B[n][k]  (B transposed, fp16 in, fp32 accum)
// flags: 1=relu, 2=store fp16, 16=transposed fp16 store (C[col*ldc+row])
__global__ __launch_bounds__(256)
void gemm_bt(const ushort* __restrict__ A, int lda, long long sA,
             const ushort* __restrict__ B, int ldb, long long sB,
             const float* __restrict__ bias,
             void* __restrict__ C, int ldc, long long sC,
             int K, int flags)
{
  __shared__ ushort As[128 * 32];
  __shared__ ushort Bs[128 * 32];
  const int z = blockIdx.z;
  A += (long long)z * sA;
  B += (long long)z * sB;
  const int tid  = threadIdx.x;
  const int lane = tid & 63;
  const int wave = tid >> 6;
  const int wm   = (wave >> 1) * 64;
  const int wn   = (wave & 1) * 64;
  const long long bm = (long long)blockIdx.y * 128;
  const long long bn = (long long)blockIdx.x * 128;

  const int srow = tid >> 2;
  const int skq  = (tid & 3) * 8;
  const ushort* a0 = A + (bm + srow) * lda + skq;
  const ushort* a1 = a0 + 64LL * lda;
  const ushort* b0 = B + (bn + srow) * ldb + skq;
  const ushort* b1 = b0 + 64LL * ldb;
  ushort* lA0 = &As[tid * 8];
  ushort* lA1 = &As[2048 + tid * 8];
  ushort* lB0 = &Bs[tid * 8];
  ushort* lB1 = &Bs[2048 + tid * 8];

  fx4 acc[4][4] = {};
  const ushort* ap = &As[(wm + (lane & 15)) * 32 + (lane >> 4) * 8];
  const ushort* bp = &Bs[(wn + (lane & 15)) * 32 + (lane >> 4) * 8];

  for (int k0 = 0; k0 < K; k0 += 32) {
    gload_lds16(a0, lA0);
    gload_lds16(a1, lA1);
    gload_lds16(b0, lB0);
    gload_lds16(b1, lB1);
    a0 += 32; a1 += 32; b0 += 32; b1 += 32;
    __syncthreads();
    half8 af[4], bv[4];
#pragma unroll
    for (int t = 0; t < 4; ++t) {
      af[t] = *(const half8*)(ap + t * 16 * 32);
      bv[t] = *(const half8*)(bp + t * 16 * 32);
    }
#pragma unroll
    for (int i = 0; i < 4; ++i)
#pragma unroll
      for (int j = 0; j < 4; ++j)
        acc[i][j] = MFMA16(af[i], bv[j], acc[i][j]);
    __syncthreads();
  }

  const int col0 = (int)bn + wn + (lane & 15);
  const int row0 = (int)bm + wm + ((lane >> 4) << 2);

  if (flags & 16) {
    ushort* Ch = (ushort*)C + (long long)z * sC;
#pragma unroll
    for (int j = 0; j < 4; ++j) {
      const int col = col0 + j * 16;
      const float bvv = bias ? bias[col] : 0.0f;
#pragma unroll
      for (int i = 0; i < 4; ++i) {
        const int row = row0 + i * 16;
        ushort4 o;
        o.x = f2h(acc[i][j][0] + bvv);
        o.y = f2h(acc[i][j][1] + bvv);
        o.z = f2h(acc[i][j][2] + bvv);
        o.w = f2h(acc[i][j][3] + bvv);
        *(ushort4*)(Ch + (long long)col * ldc + row) = o;
      }
    }
    return;
  }

  float*  Cf = (float*)C + (long long)z * sC;
  ushort* Ch = (ushort*)C + (long long)z * sC;
#pragma unroll
  for (int j = 0; j < 4; ++j) {
    const int col = col0 + j * 16;
    const float bvv = bias ? bias[col] : 0.0f;
#pragma unroll
    for (int i = 0; i < 4; ++i) {
      const long long row = row0 + i * 16;
#pragma unroll
      for (int r = 0; r < 4; ++r) {
        float v = acc[i][j][r] + bvv;
        if (flags & 1) v = fmaxf(v, 0.0f);
        if (flags & 2) Ch[(row + r) * ldc + col] = f2h(v);
        else           Cf[(row + r) * ldc + col] = v;
      }
    }
  }
}

// Single-pass flash attention, online row-max. Block = (batch, 64-row Q-tile),
// 512 threads / 8 waves. QK: wave w computes S[qw=w>>2][tw=w&3] 32x32 subtile;
// PV: wave w owns d-slice [w*64, w*64+64) over all 64 q rows.
// K and V MFMA B-frags load DIRECTLY from global (L2-resident) - no LDS staging.
// LDS: Q (padded, stride 40) + P (16KB) + softmax state. 3 barriers/tile.
__global__ __launch_bounds__(512, 2)
void attn_fused(const ushort* __restrict__ KQ, const ushort* __restrict__ EMBT,
                float* __restrict__ out)
{
  __shared__ ushort Qs[20480];   // [dc 8][64 q][40]
  __shared__ ushort Ps[10240];   // [kc 4][64 q][40]
  __shared__ float  rmax[256];   // [tw 4][64 q]
  __shared__ float  mstate[64];
  __shared__ float  mnewA[64];
  __shared__ float  alphaA[64];  // reused as linv in epilogue
  __shared__ float  lred[256];   // [tw 4][64 q]

  const int tid  = threadIdx.x;
  const int lane = tid & 63;
  const int w    = tid >> 6;
  const int c    = lane & 15;
  const int q4   = lane >> 4;
  const int qw   = w >> 2;       // 0..1
  const int tw   = w & 3;        // 0..3
  const int dw   = w * 64;       // d-slice base
  const int z    = blockIdx.x;   // batch -> XCD locality (x fastest)
  const long long tb = (long long)z * 2048;
  const int q0   = blockIdx.y * 64;

  // stage Q (rows q0..q0+63, cols 256..511 of KQ) into padded LDS
#pragma unroll
  for (int p = 0; p < 4; ++p) {
    const int cu  = p * 512 + tid;       // 0..2047
    const int row = cu >> 5;             // 0..63
    const int kch = cu & 31;
    const int dc  = kch >> 2, qg = kch & 3;
    const half8 v = *(const half8*)(KQ + (tb + q0 + row) * 512 + 256 + dc * 32 + qg * 8);
    *(half8*)(Qs + dc * 2560 + row * 40 + qg * 8) = v;
  }
  if (tid < 64) mstate[tid] = -3.0e38f;
  __syncthreads();

  float l_part[2][4] = {};
  fx4 o[4][4] = {};

  for (int t0 = 0; t0 < 2048; t0 += 128) {
    // ---- QK: S[2 i][2 j], K b-frags straight from global ----
    fx4 s[2][2] = {};
    const ushort* kb0 = KQ + (tb + t0 + tw * 32 + c) * 512;
    const ushort* kb1 = kb0 + 16 * 512;
#pragma unroll
    for (int dc = 0; dc < 8; ++dc) {
      const half8 a0 = *(const half8*)(Qs + dc * 2560 + (qw * 32 + c) * 40 + q4 * 8);
      const half8 a1 = *(const half8*)(Qs + dc * 2560 + (qw * 32 + 16 + c) * 40 + q4 * 8);
      const half8 b0 = *(const half8*)(kb0 + dc * 32 + q4 * 8);
      const half8 b1 = *(const half8*)(kb1 + dc * 32 + q4 * 8);
      s[0][0] = MFMA16(a0, b0, s[0][0]); s[0][1] = MFMA16(a0, b1, s[0][1]);
      s[1][0] = MFMA16(a1, b0, s[1][0]); s[1][1] = MFMA16(a1, b1, s[1][1]);
    }
    // ---- local row max over this wave's 32 tok ----
#pragma unroll
    for (int i = 0; i < 2; ++i) {
      fx4 rm;
#pragma unroll
      for (int r = 0; r < 4; ++r) rm[r] = fmaxf(s[i][0][r], s[i][1][r]);
#pragma unroll
      for (int off = 1; off < 16; off <<= 1)
#pragma unroll
        for (int r = 0; r < 4; ++r) rm[r] = fmaxf(rm[r], __shfl_xor(rm[r], off, 64));
      if (c == 0) {
#pragma unroll
        for (int r = 0; r < 4; ++r)
          rmax[tw * 64 + qw * 32 + i * 16 + q4 * 4 + r] = rm[r];
      }
    }
    __syncthreads();
    if (w == 0) {   // lane = q row
      const float mo = mstate[lane];
      float mn = fmaxf(fmaxf(rmax[lane], rmax[64 + lane]),
                       fmaxf(rmax[128 + lane], rmax[192 + lane]));
      mn = fmaxf(mn, mo);
      mnewA[lane]  = mn;
      alphaA[lane] = __expf(mo - mn);
      mstate[lane] = mn;
    }
    __syncthreads();
    // ---- P = exp(s - m) fp16 -> LDS ; l update ; O rescale ----
#pragma unroll
    for (int i = 0; i < 2; ++i)
#pragma unroll
      for (int r = 0; r < 4; ++r) {
        const int q = qw * 32 + i * 16 + q4 * 4 + r;
        const float mn = mnewA[q];
        const float e0 = __expf(s[i][0][r] - mn);
        const float e1 = __expf(s[i][1][r] - mn);
        l_part[i][r] = alphaA[q] * l_part[i][r] + e0 + e1;
        Ps[tw * 2560 + q * 40 + c]      = f2h(e0);
        Ps[tw * 2560 + q * 40 + 16 + c] = f2h(e1);
      }
#pragma unroll
    for (int i4 = 0; i4 < 4; ++i4)
#pragma unroll
      for (int r = 0; r < 4; ++r) {
        const float aq = alphaA[i4 * 16 + q4 * 4 + r];
#pragma unroll
        for (int n = 0; n < 4; ++n) o[i4][n][r] *= aq;
      }
    __syncthreads();
    // ---- PV: a-frags from Ps, V b-frags straight from global EMBT ----
#pragma unroll
    for (int kc = 0; kc < 4; ++kc) {
      half8 vb[4];
#pragma unroll
      for (int n = 0; n < 4; ++n)
        vb[n] = *(const half8*)(EMBT + (long long)(dw + n * 16 + c) * 16384 +
                                tb + t0 + kc * 32 + q4 * 8);
      half8 pa[4];
#pragma unroll
      for (int i4 = 0; i4 < 4; ++i4)
        pa[i4] = *(const half8*)(Ps + kc * 2560 + (i4 * 16 + c) * 40 + q4 * 8);
#pragma unroll
      for (int i4 = 0; i4 < 4; ++i4)
#pragma unroll
        for (int n = 0; n < 4; ++n)
          o[i4][n] = MFMA16(pa[i4], vb[n], o[i4][n]);
    }
  }

  // ---- epilogue: finalize l, normalize, store ----
#pragma unroll
  for (int i = 0; i < 2; ++i) {
    fx4 lv;
#pragma unroll
    for (int r = 0; r < 4; ++r) lv[r] = l_part[i][r];
#pragma unroll
    for (int off = 1; off < 16; off <<= 1)
#pragma unroll
      for (int r = 0; r < 4; ++r) lv[r] += __shfl_xor(lv[r], off, 64);
    if (c == 0) {
#pragma unroll
      for (int r = 0; r < 4; ++r)
        lred[tw * 64 + qw * 32 + i * 16 + q4 * 4 + r] = lv[r];
    }
  }
  __syncthreads();
  if (w == 0)
    alphaA[lane] = 1.0f / (lred[lane] + lred[64 + lane] + lred[128 + lane] + lred[192 + lane]);
  __syncthreads();

  float* ob = out + (tb + q0) * 512 + dw;
#pragma unroll
  for (int i4 = 0; i4 < 4; ++i4)
#pragma unroll
    for (int r = 0; r < 4; ++r) {
      const int q = i4 * 16 + q4 * 4 + r;
      const float li = alphaA[q];
#pragma unroll
      for (int n = 0; n < 4; ++n)
        ob[(long long)q * 512 + n * 16 + c] = o[i4][n][r] * li;
    }
}

// fp32 [R][C] -> fp16 [C][R]
__global__ __launch_bounds__(256)
void transpose_cast_w(const float* __restrict__ in, ushort* __restrict__ out, int R, int C) {
  __shared__ float tile[32][33];
  const int c0 = blockIdx.x * 32, r0 = blockIdx.y * 32;
  const int tx = threadIdx.x & 31, ty = threadIdx.x >> 5;
#pragma unroll
  for (int i = 0; i < 32; i += 8)
    tile[ty + i][tx] = in[(long long)(r0 + ty + i) * C + (c0 + tx)];
  __syncthreads();
#pragma unroll
  for (int i = 0; i < 32; i += 8)
    out[(long long)(c0 + ty + i) * R + (r0 + tx)] = f2h(tile[tx][ty + i]);
}

__global__ __launch_bounds__(256)
void cast_f32_f16(const float* __restrict__ in, ushort* __restrict__ out) {
  const long long i = ((long long)blockIdx.x * 256 + threadIdx.x) * 4;
  const float4 v = *(const float4*)(in + i);
  ushort4 o;
  o.x = f2h(v.x); o.y = f2h(v.y); o.z = f2h(v.z); o.w = f2h(v.w);
  *(ushort4*)(out + i) = o;
}

__global__ __launch_bounds__(256)
void concat_bias(const float* __restrict__ b0, const float* __restrict__ b1,
                 float* __restrict__ out) {
  const int i = blockIdx.x * 256 + threadIdx.x;
  out[i] = (i < 1024) ? b0[i] : b1[i - 1024];
}

extern "C" void kernel_launch(void* const* d_in, const int* in_sizes, int n_in,
                              void* d_out, int out_size, void* d_ws, size_t ws_size,
                              hipStream_t stream) {
  (void)in_sizes; (void)n_in; (void)out_size; (void)ws_size;
  const float* x   = (const float*)d_in[0];
  const float* We1 = (const float*)d_in[1];
  const float* be1 = (const float*)d_in[2];
  const float* We2 = (const float*)d_in[3];
  const float* be2 = (const float*)d_in[4];
  const float* Wk1 = (const float*)d_in[5];
  const float* bk1 = (const float*)d_in[6];
  const float* Wk2 = (const float*)d_in[7];
  const float* bk2 = (const float*)d_in[8];
  float* out = (float*)d_out;
  char* ws = (char*)d_ws;

  ushort* Xb   = (ushort*)(ws + 0);            // 16.78 MB, dead after gemm1
  ushort* W2c  = (ushort*)(ws + 0);            // 2 MB, written after gemm1
  ushort* H    = (ushort*)(ws + 16777216);     // 16384x2048 fp16 = 67.1 MB
  ushort* EMBT = (ushort*)(ws + 83886080);     // [512][16384] fp16 = 16.78 MB
  ushort* KQ   = (ushort*)(ws + 100663296);    // 16384x512 fp16 = 16.78 MB
  float*  b1c  = (float*)(ws + 117440512);     // 2048 fp32
  ushort* W1c  = (ushort*)(ws + 117448704);    // 2 MB

  cast_f32_f16<<<dim3(8192), 256, 0, stream>>>(x, Xb);
  transpose_cast_w<<<dim3(32, 16), 256, 0, stream>>>(We1, W1c, 512, 1024);
  transpose_cast_w<<<dim3(32, 16), 256, 0, stream>>>(Wk1, W1c + 524288, 512, 1024);
  concat_bias<<<dim3(8), 256, 0, stream>>>(be1, bk1, b1c);

  // H = relu(x @ [We1|Wk1] + [be1|bk1])   [16384,2048]
  gemm_bt<<<dim3(16, 128, 1), 256, 0, stream>>>(Xb, 512, 0, W1c, 512, 0, b1c,
                                                H, 2048, 0, 512, 1 | 2);

  transpose_cast_w<<<dim3(16, 32), 256, 0, stream>>>(We2, W2c, 1024, 512);
  transpose_cast_w<<<dim3(16, 32), 256, 0, stream>>>(Wk2, W2c + 524288, 1024, 512);

  // EMBT[d][tok] = (H[:, :1024] @ We2 + be2)^T
  gemm_bt<<<dim3(4, 128, 1), 256, 0, stream>>>(H, 2048, 0, W2c, 1024, 0, be2,
                                               EMBT, 16384, 0, 1024, 16);
  // KQ = H[:, 1024:] @ Wk2 + bk2
  gemm_bt<<<dim3(4, 128, 1), 256, 0, stream>>>(H + 1024, 2048, 0, W2c + 524288, 1024, 0, bk2,
                                               KQ, 512, 0, 1024, 2);

  // fused single-pass flash attention: grid x=batch (XCD-local), y=64-row Q-tile
  attn_fused<<<dim3(8, 32), 512, 0, stream>>>(KQ, EMBT, out);
}

// Round 7
// 353.934 us; speedup vs baseline: 1.1042x; 1.1042x over previous
//
#include <hip/hip_runtime.h>
#include <stdint.h>

using fx4   = __attribute__((ext_vector_type(4))) float;
using half8 = __attribute__((ext_vector_type(8))) _Float16;

__device__ __forceinline__ ushort f2h(float x) {
  _Float16 h = (_Float16)x;
  union { _Float16 hv; ushort u; } v; v.hv = h;
  return v.u;
}

__device__ __forceinline__ void gload_lds16(const ushort* g, ushort* l) {
  __builtin_amdgcn_global_load_lds(
      (__attribute__((address_space(1))) const void*)g,
      (__attribute__((address_space(3))) void*)l, 16, 0, 0);
}

#define MFMA16(a, b, c) __builtin_amdgcn_mfma_f32_16x16x32_f16(a, b, c, 0, 0, 0)

// Shared GEMM body. C[m][n] = sum_k A[m][k]*B[n][k] (B transposed, fp16, fp32 acc)
// flags: 1=relu, 2=store fp16, 16=transposed fp16 store (C[col*ldc+row])
__device__ __forceinline__ void gemm_body(
    const ushort* __restrict__ A, int lda,
    const ushort* __restrict__ B, int ldb,
    const float* __restrict__ bias,
    void* __restrict__ C, int ldc,
    int K, int flags, int bx, int by,
    ushort* As, ushort* Bs)
{
  const int tid  = threadIdx.x;
  const int lane = tid & 63;
  const int wave = tid >> 6;
  const int wm   = (wave >> 1) * 64;
  const int wn   = (wave & 1) * 64;
  const long long bm = (long long)by * 128;
  const long long bn = (long long)bx * 128;

  const int srow = tid >> 2;
  const int skq  = (tid & 3) * 8;
  const ushort* a0 = A + (bm + srow) * lda + skq;
  const ushort* a1 = a0 + 64LL * lda;
  const ushort* b0 = B + (bn + srow) * ldb + skq;
  const ushort* b1 = b0 + 64LL * ldb;
  ushort* lA0 = &As[tid * 8];
  ushort* lA1 = &As[2048 + tid * 8];
  ushort* lB0 = &Bs[tid * 8];
  ushort* lB1 = &Bs[2048 + tid * 8];

  fx4 acc[4][4] = {};
  const ushort* ap = &As[(wm + (lane & 15)) * 32 + (lane >> 4) * 8];
  const ushort* bp = &Bs[(wn + (lane & 15)) * 32 + (lane >> 4) * 8];

  for (int k0 = 0; k0 < K; k0 += 32) {
    gload_lds16(a0, lA0);
    gload_lds16(a1, lA1);
    gload_lds16(b0, lB0);
    gload_lds16(b1, lB1);
    a0 += 32; a1 += 32; b0 += 32; b1 += 32;
    __syncthreads();
    half8 af[4], bv[4];
#pragma unroll
    for (int t = 0; t < 4; ++t) {
      af[t] = *(const half8*)(ap + t * 16 * 32);
      bv[t] = *(const half8*)(bp + t * 16 * 32);
    }
#pragma unroll
    for (int i = 0; i < 4; ++i)
#pragma unroll
      for (int j = 0; j < 4; ++j)
        acc[i][j] = MFMA16(af[i], bv[j], acc[i][j]);
    __syncthreads();
  }

  const int col0 = (int)bn + wn + (lane & 15);
  const int row0 = (int)bm + wm + ((lane >> 4) << 2);

  if (flags & 16) {
    ushort* Ch = (ushort*)C;
#pragma unroll
    for (int j = 0; j < 4; ++j) {
      const int col = col0 + j * 16;
      const float bvv = bias ? bias[col] : 0.0f;
#pragma unroll
      for (int i = 0; i < 4; ++i) {
        const int row = row0 + i * 16;
        ushort4 o;
        o.x = f2h(acc[i][j][0] + bvv);
        o.y = f2h(acc[i][j][1] + bvv);
        o.z = f2h(acc[i][j][2] + bvv);
        o.w = f2h(acc[i][j][3] + bvv);
        *(ushort4*)(Ch + (long long)col * ldc + row) = o;
      }
    }
    return;
  }

  float*  Cf = (float*)C;
  ushort* Ch = (ushort*)C;
#pragma unroll
  for (int j = 0; j < 4; ++j) {
    const int col = col0 + j * 16;
    const float bvv = bias ? bias[col] : 0.0f;
#pragma unroll
    for (int i = 0; i < 4; ++i) {
      const long long row = row0 + i * 16;
#pragma unroll
      for (int r = 0; r < 4; ++r) {
        float v = acc[i][j][r] + bvv;
        if (flags & 1) v = fmaxf(v, 0.0f);
        if (flags & 2) Ch[(row + r) * ldc + col] = f2h(v);
        else           Cf[(row + r) * ldc + col] = v;
      }
    }
  }
}

__global__ __launch_bounds__(256)
void gemm_bt(const ushort* __restrict__ A, int lda, long long sA,
             const ushort* __restrict__ B, int ldb, long long sB,
             const float* __restrict__ bias,
             void* __restrict__ C, int ldc, long long sC,
             int K, int flags)
{
  __shared__ ushort As[128 * 32];
  __shared__ ushort Bs[128 * 32];
  const int z = blockIdx.z;
  void* Cz = (flags & (2 | 16)) ? (void*)((ushort*)C + (long long)z * sC)
                                : (void*)((float*)C + (long long)z * sC);
  gemm_body(A + (long long)z * sA, lda, B + (long long)z * sB, ldb, bias,
            Cz, ldc, K, flags, blockIdx.x, blockIdx.y, As, Bs);
}

// z=0: EMBT = (H[:,:1024] @ We2 + be2)^T ; z=1: KQ = H[:,1024:] @ Wk2 + bk2
__global__ __launch_bounds__(256)
void gemm2_pair(const ushort* __restrict__ H, const ushort* __restrict__ W2c,
                const float* __restrict__ be2, const float* __restrict__ bk2,
                ushort* __restrict__ EMBT, ushort* __restrict__ KQ)
{
  __shared__ ushort As[128 * 32];
  __shared__ ushort Bs[128 * 32];
  if (blockIdx.z == 0)
    gemm_body(H, 2048, W2c, 1024, be2, EMBT, 16384, 1024, 16,
              blockIdx.x, blockIdx.y, As, Bs);
  else
    gemm_body(H + 1024, 2048, W2c + 524288, 1024, bk2, KQ, 512, 1024, 2,
              blockIdx.x, blockIdx.y, As, Bs);
}

// Single-pass flash attention, online row-max. Block = (batch, 64-row Q-tile),
// 512 threads / 8 waves. QK: wave w -> S subtile [qw 32q][tw 32tok];
// PV: wave w -> d-slice [w*64, w*64+64). K/V b-frags DIRECT from global (L2),
// hoisted into register arrays for 16-deep outstanding loads.
__global__ __launch_bounds__(512, 2)
void attn_fused(const ushort* __restrict__ KQ, const ushort* __restrict__ EMBT,
                float* __restrict__ out)
{
  __shared__ ushort Qs[20480];   // [dc 8][64 q][40]
  __shared__ ushort Ps[10240];   // [kc 4][64 q][40]
  __shared__ float  rmax[256];   // [tw 4][64 q]
  __shared__ float  mstate[64];
  __shared__ float  mnewA[64];
  __shared__ float  alphaA[64];  // reused as linv in epilogue
  __shared__ float  lred[256];   // [tw 4][64 q]

  const int tid  = threadIdx.x;
  const int lane = tid & 63;
  const int w    = tid >> 6;
  const int c    = lane & 15;
  const int q4   = lane >> 4;
  const int qw   = w >> 2;       // 0..1
  const int tw   = w & 3;        // 0..3
  const int dw   = w * 64;       // d-slice base
  const int z    = blockIdx.x;   // batch -> XCD locality (x fastest)
  const long long tb = (long long)z * 2048;
  const int q0   = blockIdx.y * 64;

  // stage Q (rows q0..q0+63, cols 256..511 of KQ) into padded LDS
#pragma unroll
  for (int p = 0; p < 4; ++p) {
    const int cu  = p * 512 + tid;       // 0..2047
    const int row = cu >> 5;             // 0..63
    const int kch = cu & 31;
    const int dc  = kch >> 2, qg = kch & 3;
    const half8 v = *(const half8*)(KQ + (tb + q0 + row) * 512 + 256 + dc * 32 + qg * 8);
    *(half8*)(Qs + dc * 2560 + row * 40 + qg * 8) = v;
  }
  if (tid < 64) mstate[tid] = -3.0e38f;
  __syncthreads();

  float l_part[2][4] = {};
  fx4 o[4][4] = {};

  for (int t0 = 0; t0 < 2048; t0 += 128) {
    // ---- hoist all 16 K b-frags into registers, then QK MFMAs ----
    half8 kb[2][8];
    const ushort* kb0 = KQ + (tb + t0 + tw * 32 + c) * 512;
    const ushort* kb1 = kb0 + 16 * 512;
#pragma unroll
    for (int dc = 0; dc < 8; ++dc) {
      kb[0][dc] = *(const half8*)(kb0 + dc * 32 + q4 * 8);
      kb[1][dc] = *(const half8*)(kb1 + dc * 32 + q4 * 8);
    }
    fx4 s[2][2] = {};
#pragma unroll
    for (int dc = 0; dc < 8; ++dc) {
      const half8 a0 = *(const half8*)(Qs + dc * 2560 + (qw * 32 + c) * 40 + q4 * 8);
      const half8 a1 = *(const half8*)(Qs + dc * 2560 + (qw * 32 + 16 + c) * 40 + q4 * 8);
      s[0][0] = MFMA16(a0, kb[0][dc], s[0][0]); s[0][1] = MFMA16(a0, kb[1][dc], s[0][1]);
      s[1][0] = MFMA16(a1, kb[0][dc], s[1][0]); s[1][1] = MFMA16(a1, kb[1][dc], s[1][1]);
    }
    // ---- issue all 16 V b-frag loads NOW (latency hidden by softmax phase) ----
    half8 vb[4][4];
#pragma unroll
    for (int kc = 0; kc < 4; ++kc)
#pragma unroll
      for (int n = 0; n < 4; ++n)
        vb[kc][n] = *(const half8*)(EMBT + (long long)(dw + n * 16 + c) * 16384 +
                                    tb + t0 + kc * 32 + q4 * 8);
    // ---- local row max over this wave's 32 tok ----
#pragma unroll
    for (int i = 0; i < 2; ++i) {
      fx4 rm;
#pragma unroll
      for (int r = 0; r < 4; ++r) rm[r] = fmaxf(s[i][0][r], s[i][1][r]);
#pragma unroll
      for (int off = 1; off < 16; off <<= 1)
#pragma unroll
        for (int r = 0; r < 4; ++r) rm[r] = fmaxf(rm[r], __shfl_xor(rm[r], off, 64));
      if (c == 0) {
#pragma unroll
        for (int r = 0; r < 4; ++r)
          rmax[tw * 64 + qw * 32 + i * 16 + q4 * 4 + r] = rm[r];
      }
    }
    __syncthreads();
    if (w == 0) {   // lane = q row
      const float mo = mstate[lane];
      float mn = fmaxf(fmaxf(rmax[lane], rmax[64 + lane]),
                       fmaxf(rmax[128 + lane], rmax[192 + lane]));
      mn = fmaxf(mn, mo);
      mnewA[lane]  = mn;
      alphaA[lane] = __expf(mo - mn);
      mstate[lane] = mn;
    }
    __syncthreads();
    // ---- P = exp(s - m) fp16 -> LDS ; l update ; O rescale ----
#pragma unroll
    for (int i = 0; i < 2; ++i)
#pragma unroll
      for (int r = 0; r < 4; ++r) {
        const int q = qw * 32 + i * 16 + q4 * 4 + r;
        const float mn = mnewA[q];
        const float e0 = __expf(s[i][0][r] - mn);
        const float e1 = __expf(s[i][1][r] - mn);
        l_part[i][r] = alphaA[q] * l_part[i][r] + e0 + e1;
        Ps[tw * 2560 + q * 40 + c]      = f2h(e0);
        Ps[tw * 2560 + q * 40 + 16 + c] = f2h(e1);
      }
#pragma unroll
    for (int i4 = 0; i4 < 4; ++i4)
#pragma unroll
      for (int r = 0; r < 4; ++r) {
        const float aq = alphaA[i4 * 16 + q4 * 4 + r];
#pragma unroll
        for (int n = 0; n < 4; ++n) o[i4][n][r] *= aq;
      }
    __syncthreads();
    // ---- PV: a-frags from Ps, V b-frags already in registers ----
#pragma unroll
    for (int kc = 0; kc < 4; ++kc) {
      half8 pa[4];
#pragma unroll
      for (int i4 = 0; i4 < 4; ++i4)
        pa[i4] = *(const half8*)(Ps + kc * 2560 + (i4 * 16 + c) * 40 + q4 * 8);
#pragma unroll
      for (int i4 = 0; i4 < 4; ++i4)
#pragma unroll
        for (int n = 0; n < 4; ++n)
          o[i4][n] = MFMA16(pa[i4], vb[kc][n], o[i4][n]);
    }
  }

  // ---- epilogue: finalize l, normalize, store ----
#pragma unroll
  for (int i = 0; i < 2; ++i) {
    fx4 lv;
#pragma unroll
    for (int r = 0; r < 4; ++r) lv[r] = l_part[i][r];
#pragma unroll
    for (int off = 1; off < 16; off <<= 1)
#pragma unroll
      for (int r = 0; r < 4; ++r) lv[r] += __shfl_xor(lv[r], off, 64);
    if (c == 0) {
#pragma unroll
      for (int r = 0; r < 4; ++r)
        lred[tw * 64 + qw * 32 + i * 16 + q4 * 4 + r] = lv[r];
    }
  }
  __syncthreads();
  if (w == 0)
    alphaA[lane] = 1.0f / (lred[lane] + lred[64 + lane] + lred[128 + lane] + lred[192 + lane]);
  __syncthreads();

  float* ob = out + (tb + q0) * 512 + dw;
#pragma unroll
  for (int i4 = 0; i4 < 4; ++i4)
#pragma unroll
    for (int r = 0; r < 4; ++r) {
      const int q = i4 * 16 + q4 * 4 + r;
      const float li = alphaA[q];
#pragma unroll
      for (int n = 0; n < 4; ++n)
        ob[(long long)q * 512 + n * 16 + c] = o[i4][n][r] * li;
    }
}

// fp32 [R][C] -> fp16 [C][R], two inputs selected by blockIdx.z
__global__ __launch_bounds__(256)
void transpose_cast_w2(const float* __restrict__ in0, const float* __restrict__ in1,
                       ushort* __restrict__ out0, ushort* __restrict__ out1,
                       int R, int C) {
  __shared__ float tile[32][33];
  const float* in  = blockIdx.z ? in1 : in0;
  ushort*      outp = blockIdx.z ? out1 : out0;
  const int c0 = blockIdx.x * 32, r0 = blockIdx.y * 32;
  const int tx = threadIdx.x & 31, ty = threadIdx.x >> 5;
#pragma unroll
  for (int i = 0; i < 32; i += 8)
    tile[ty + i][tx] = in[(long long)(r0 + ty + i) * C + (c0 + tx)];
  __syncthreads();
#pragma unroll
  for (int i = 0; i < 32; i += 8)
    outp[(long long)(c0 + ty + i) * R + (r0 + tx)] = f2h(tile[tx][ty + i]);
}

__global__ __launch_bounds__(256)
void cast_f32_f16(const float* __restrict__ in, ushort* __restrict__ out) {
  const long long i = ((long long)blockIdx.x * 256 + threadIdx.x) * 4;
  const float4 v = *(const float4*)(in + i);
  ushort4 o;
  o.x = f2h(v.x); o.y = f2h(v.y); o.z = f2h(v.z); o.w = f2h(v.w);
  *(ushort4*)(out + i) = o;
}

__global__ __launch_bounds__(256)
void concat_bias(const float* __restrict__ b0, const float* __restrict__ b1,
                 float* __restrict__ out) {
  const int i = blockIdx.x * 256 + threadIdx.x;
  out[i] = (i < 1024) ? b0[i] : b1[i - 1024];
}

extern "C" void kernel_launch(void* const* d_in, const int* in_sizes, int n_in,
                              void* d_out, int out_size, void* d_ws, size_t ws_size,
                              hipStream_t stream) {
  (void)in_sizes; (void)n_in; (void)out_size; (void)ws_size;
  const float* x   = (const float*)d_in[0];
  const float* We1 = (const float*)d_in[1];
  const float* be1 = (const float*)d_in[2];
  const float* We2 = (const float*)d_in[3];
  const float* be2 = (const float*)d_in[4];
  const float* Wk1 = (const float*)d_in[5];
  const float* bk1 = (const float*)d_in[6];
  const float* Wk2 = (const float*)d_in[7];
  const float* bk2 = (const float*)d_in[8];
  float* out = (float*)d_out;
  char* ws = (char*)d_ws;

  ushort* Xb   = (ushort*)(ws + 0);            // 16.78 MB, dead after gemm1
  ushort* W2c  = (ushort*)(ws + 0);            // 2 MB, written after gemm1
  ushort* H    = (ushort*)(ws + 16777216);     // 16384x2048 fp16 = 67.1 MB
  ushort* EMBT = (ushort*)(ws + 83886080);     // [512][16384] fp16 = 16.78 MB
  ushort* KQ   = (ushort*)(ws + 100663296);    // 16384x512 fp16 = 16.78 MB
  float*  b1c  = (float*)(ws + 117440512);     // 2048 fp32
  ushort* W1c  = (ushort*)(ws + 117448704);    // 2 MB

  cast_f32_f16<<<dim3(8192), 256, 0, stream>>>(x, Xb);
  transpose_cast_w2<<<dim3(32, 16, 2), 256, 0, stream>>>(We1, Wk1, W1c, W1c + 524288, 512, 1024);
  concat_bias<<<dim3(8), 256, 0, stream>>>(be1, bk1, b1c);

  // H = relu(x @ [We1|Wk1] + [be1|bk1])   [16384,2048]
  gemm_bt<<<dim3(16, 128, 1), 256, 0, stream>>>(Xb, 512, 0, W1c, 512, 0, b1c,
                                                H, 2048, 0, 512, 1 | 2);

  transpose_cast_w2<<<dim3(16, 32, 2), 256, 0, stream>>>(We2, Wk2, W2c, W2c + 524288, 1024, 512);

  // z=0: EMBT = (H[:,:1024]@We2+be2)^T ; z=1: KQ = H[:,1024:]@Wk2+bk2
  gemm2_pair<<<dim3(4, 128, 2), 256, 0, stream>>>(H, W2c, be2, bk2, EMBT, KQ);

  // fused single-pass flash attention: grid x=batch (XCD-local), y=64-row Q-tile
  attn_fused<<<dim3(8, 32), 512, 0, stream>>>(KQ, EMBT, out);
}